// Round 2
// baseline (571.288 us; speedup 1.0000x reference)
//
#include <hip/hip_runtime.h>
#include <hip/hip_bf16.h>
#include <math.h>

// MoE top-2 of 8 experts, D=1024, FF=2048 (SwiGLU), T=4096 tokens.
// Pipeline: router(+x cast) -> prefix -> tcast_fast weights -> GEMM1
// (gather A, fused SwiGLU*w -> U bf16) -> GEMM2 (plain stores -> Y) ->
// combine (Y rows + weighted b2 -> out).
// R2: XOR-swizzled LDS in GEMMs (bank conflicts 3.3e7 -> 0).
// R3: vectorized transpose-cast; GEMM2 plain stores + combine kernel.
// R4: GEMM1 ported to the 256-row 8-phase schedule (T3+T4+T5):
//     BM=256 x 128 f-cols (256 B-rows a/g-interleaved per wave), BK=64,
//     512 thr / 8 waves, double-buffered LDS, raw s_barrier (no vmcnt(0)
//     drain), counted s_waitcnt vmcnt(4) once per K-tile, s_setprio(1)
//     around each 16-MFMA cluster.
// R5: de-risk after container failure: LDS trimmed to exactly 128 KiB
//     (template-verified size) by dropping stok/sw shared arrays; token
//     ids and combine weights now loaded directly (guarded) from global.

#define T_TOK  4096
#define DMODEL 1024
#define NEXP   8
#define FF     2048
#define FF2    4096
#define NT1    16          // DMODEL / 64 K-tiles in GEMM1

typedef __bf16 bf16_t;
typedef bf16_t bf16x8 __attribute__((ext_vector_type(8)));
typedef float  f32x4  __attribute__((ext_vector_type(4)));

__device__ __forceinline__ void gload_lds16(const void* g, void* l) {
  __builtin_amdgcn_global_load_lds((const __attribute__((address_space(1))) void*)g,
                                   (__attribute__((address_space(3))) void*)l, 16, 0, 0);
}

// raw workgroup barrier WITHOUT the __syncthreads vmcnt(0) drain; compiler
// memory fences pin LDS/global ops on their side of the barrier.
#define BARF() do { asm volatile("" ::: "memory"); \
                    __builtin_amdgcn_s_barrier();  \
                    asm volatile("" ::: "memory"); } while (0)

// ---------------- router: logits, top-2 softmax, bucket-append, x->bf16, slot map
__global__ __launch_bounds__(256) void moe_router(
    const float* __restrict__ x, const float* __restrict__ Wr,
    const float* __restrict__ temp,
    bf16_t* __restrict__ xb,
    int* __restrict__ cnt, int* __restrict__ tok_list, float* __restrict__ w_list,
    int* __restrict__ slot)
{
  __shared__ float sWr[DMODEL * NEXP];   // 32 KB, whole router weight
  for (int i = threadIdx.x; i < DMODEL * NEXP; i += 256) sWr[i] = Wr[i];
  __syncthreads();

  int wave = threadIdx.x >> 6, lane = threadIdx.x & 63;
  int t = blockIdx.x * 4 + wave;
  const float* xr = x + (size_t)t * DMODEL;

  f32x4 acc0 = {0.f, 0.f, 0.f, 0.f}, acc1 = {0.f, 0.f, 0.f, 0.f};
  #pragma unroll
  for (int i = 0; i < 16; ++i) {
    int d = lane + 64 * i;                    // coalesced
    float v = xr[d];
    xb[(size_t)t * DMODEL + d] = (bf16_t)v;   // fused cast
    const f32x4* wr = (const f32x4*)&sWr[d * NEXP];
    acc0 += v * wr[0];
    acc1 += v * wr[1];
  }
  #pragma unroll
  for (int off = 32; off; off >>= 1) {
    #pragma unroll
    for (int q = 0; q < 4; ++q) {
      acc0[q] += __shfl_down(acc0[q], off, 64);
      acc1[q] += __shfl_down(acc1[q], off, 64);
    }
  }
  if (lane == 0) {
    float invt = 1.f / temp[0];
    float lg[NEXP] = {acc0[0], acc0[1], acc0[2], acc0[3],
                      acc1[0], acc1[1], acc1[2], acc1[3]};
    int bi = 0, si = 0;
    float best = -3.4e38f, sec = -3.4e38f;
    #pragma unroll
    for (int e = 0; e < NEXP; ++e) {
      float l = lg[e] * invt;
      if (l > best)     { sec = best; si = bi; best = l; bi = e; }
      else if (l > sec) { sec = l; si = e; }
    }
    float ex = expf(sec - best);          // top-2 softmax
    float wb  = 1.f / (1.f + ex);
    float wsc = ex  / (1.f + ex);
    int p0 = atomicAdd(&cnt[bi], 1);
    tok_list[bi * T_TOK + p0] = t; w_list[bi * T_TOK + p0] = wb;
    int p1 = atomicAdd(&cnt[si], 1);
    tok_list[si * T_TOK + p1] = t; w_list[si * T_TOK + p1] = wsc;
    slot[2 * t]     = bi * T_TOK + p0;    // expert = v>>12, pos = v&4095
    slot[2 * t + 1] = si * T_TOK + p1;
  }
}

__global__ void moe_prefix(const int* __restrict__ cnt, int* __restrict__ offs) {
  if (threadIdx.x == 0) {
    int s = 0;
    for (int e = 0; e < NEXP; ++e) { offs[e] = s; s += cnt[e]; }
    offs[NEXP] = s;
  }
}

// ---------------- transpose-cast: fp32 [R][C] -> bf16 [C][R], vectorized.
__global__ __launch_bounds__(256) void tcast_fast(
    const float* __restrict__ in, bf16_t* __restrict__ outp, int R, int C)
{
  __shared__ float tile[64][65];
  const float* inp = in + (size_t)blockIdx.z * R * C;
  bf16_t* op = outp + (size_t)blockIdx.z * R * C;
  int c0 = blockIdx.x * 64, r0 = blockIdx.y * 64;
  int tid = threadIdx.x;
  int lr = tid >> 4;            // 0..15
  int lc4 = (tid & 15) * 4;     // 0,4,..,60
  #pragma unroll
  for (int p = 0; p < 4; ++p) {
    int r = p * 16 + lr;
    const float4 v = *(const float4*)&inp[(size_t)(r0 + r) * C + c0 + lc4];
    tile[r][lc4 + 0] = v.x; tile[r][lc4 + 1] = v.y;
    tile[r][lc4 + 2] = v.z; tile[r][lc4 + 3] = v.w;
  }
  __syncthreads();
  int rr8 = (tid & 7) * 8;
  #pragma unroll
  for (int it = 0; it < 2; ++it) {
    int cc = (tid >> 3) + it * 32;
    bf16x8 o;
    #pragma unroll
    for (int j = 0; j < 8; ++j) o[j] = (bf16_t)tile[rr8 + j][cc];
    *(bf16x8*)&op[(size_t)(c0 + cc) * R + r0 + rr8] = o;
  }
}

// ---------------- GEMM1 (R4/R5): gathered x rows * W1t[e] -> SwiGLU*w -> U bf16
// 512 threads = 8 waves (2M x 4N). Block: 256 token-rows x 128 f-cols.
// B-tile = 256 W1 rows: wave wn's 64 rows = 32 a-rows + 32 g-rows, same f.
// K-loop: 4 phases/K-tile, 1 half-tile staged per phase, counted vmcnt(4).
#define STG_A1(buf, ha, kk) do { \
    gload_lds16(xb + asrc[ha][0] + (kk), &As[buf][aofs[ha][0]]); \
    gload_lds16(xb + asrc[ha][1] + (kk), &As[buf][aofs[ha][1]]); } while (0)
#define STG_B1(buf, hb, kk) do { \
    gload_lds16(W1e + bsrc[hb][0] + (kk), &Bs[buf][bofs[hb][0]]); \
    gload_lds16(W1e + bsrc[hb][1] + (kk), &Bs[buf][bofs[hb][1]]); } while (0)
#define LDA1(dst, rowbase, kh_) \
    dst = *(const bf16x8*)&As[cur][((rowbase) + l16) * 64 + ((((kh_) * 4 + quad) ^ (l16 & 7)) * 8)]
#define LDB1(dst, rowbase, kh_) \
    dst = *(const bf16x8*)&Bs[cur][((rowbase) + l16) * 64 + ((((kh_) * 4 + quad) ^ (l16 & 7)) * 8)]

__global__ __launch_bounds__(512, 2) void moe_gemm1(
    const bf16_t* __restrict__ xb, const bf16_t* __restrict__ W1t,
    const float* __restrict__ b1, const int* __restrict__ cnt,
    const int* __restrict__ offs, const int* __restrict__ tok_list,
    const float* __restrict__ w_list, bf16_t* __restrict__ U,
    int e_base, long estride)
{
  int e = e_base + blockIdx.z;
  int count = cnt[e];
  int m0 = blockIdx.y * 256;
  if (m0 >= count) return;                  // early-exit worst-case tiles
  int nt = blockIdx.x;                      // f-cols [nt*128, nt*128+128)
  const bf16_t* W1e = W1t + (size_t)blockIdx.z * estride;

  __shared__ bf16_t As[2][256 * 64];        // 64 KiB (double-buffered)
  __shared__ bf16_t Bs[2][256 * 64];        // 64 KiB  -> 128 KiB total

  int tid = threadIdx.x;
  int w = tid >> 6, lane = tid & 63;
  int wm = w >> 2, wn = w & 3;              // wave grid 2M x 4N
  int quad = lane >> 4, l16 = lane & 15;
  int rsub = lane >> 3, csub = lane & 7;
  int swz = csub ^ rsub;                    // XOR-swizzled global src chunk

  // staging addresses: half ha/hb in {0,1}, 2 row-groups of 8 per wave.
  unsigned asrc[2][2], bsrc[2][2];          // element offsets (per-lane)
  int aofs[2][2], bofs[2][2];               // LDS element offsets (wave-uniform)
  #pragma unroll
  for (int h = 0; h < 2; ++h) {
    #pragma unroll
    for (int i = 0; i < 2; ++i) {
      int rb = h * 128 + w * 16 + i * 8;    // row base, rb&7 == 0
      int r = rb + rsub;
      int gm = m0 + r;
      int tokr = (gm < count) ? tok_list[e * T_TOK + gm] : 0;  // guarded gather id
      asrc[h][i] = (unsigned)tokr * DMODEL + swz * 8;
      aofs[h][i] = rb * 64;
      int wn_r = r >> 6, j = r & 63;        // B row r -> a/g W1 row
      int f = nt * 128 + wn_r * 32 + (j & 31);
      bsrc[h][i] = (unsigned)((j < 32) ? f : (FF + f)) * DMODEL + swz * 8;
      bofs[h][i] = rb * 64;
    }
  }

  f32x4 acc[8][4];
  #pragma unroll
  for (int m = 0; m < 8; ++m)
    #pragma unroll
    for (int n = 0; n < 4; ++n) acc[m][n] = (f32x4){0.f, 0.f, 0.f, 0.f};
  bf16x8 a0[4][2], a1[4][2], bb[2][2];

  // prologue: tile0 fully, tile1 A-halves -> 12 ops; allow 4 newest in flight
  STG_A1(0, 0, 0); STG_A1(0, 1, 0);
  STG_B1(0, 0, 0); STG_B1(0, 1, 0);
  STG_A1(1, 0, 64); STG_A1(1, 1, 64);
  asm volatile("s_waitcnt vmcnt(4)" ::: "memory");
  BARF();

  for (int t = 0; t < NT1; ++t) {
    const int cur = t & 1, nxt = cur ^ 1;
    const int k1 = ((t + 1 < NT1) ? t + 1 : NT1 - 1) * 64;  // clamped tails:
    const int k2 = ((t + 2 < NT1) ? t + 2 : NT1 - 1) * 64;  // redundant identical loads

    // ---- P1: stage (t+1).B-top -> nxt; read a[mh0], b[nh0]; MFMA mh0 x nh0
    STG_B1(nxt, 0, k1);
    #pragma unroll
    for (int m = 0; m < 4; ++m)
      #pragma unroll
      for (int kh = 0; kh < 2; ++kh) LDA1(a0[m][kh], wm * 128 + m * 16, kh);
    #pragma unroll
    for (int n = 0; n < 2; ++n)
      #pragma unroll
      for (int kh = 0; kh < 2; ++kh) LDB1(bb[n][kh], wn * 64 + n * 16, kh);
    BARF();
    __builtin_amdgcn_s_setprio(1);
    #pragma unroll
    for (int m = 0; m < 4; ++m)
      #pragma unroll
      for (int n = 0; n < 2; ++n)
        #pragma unroll
        for (int kh = 0; kh < 2; ++kh)
          acc[m][n] = __builtin_amdgcn_mfma_f32_16x16x32_bf16(a0[m][kh], bb[n][kh], acc[m][n], 0, 0, 0);
    __builtin_amdgcn_s_setprio(0);
    BARF();

    // ---- P2: stage (t+1).B-bot -> nxt; read a[mh1]; MFMA mh1 x nh0
    STG_B1(nxt, 1, k1);
    #pragma unroll
    for (int m = 0; m < 4; ++m)
      #pragma unroll
      for (int kh = 0; kh < 2; ++kh) LDA1(a1[m][kh], wm * 128 + 64 + m * 16, kh);
    BARF();
    __builtin_amdgcn_s_setprio(1);
    #pragma unroll
    for (int m = 0; m < 4; ++m)
      #pragma unroll
      for (int n = 0; n < 2; ++n)
        #pragma unroll
        for (int kh = 0; kh < 2; ++kh)
          acc[4 + m][n] = __builtin_amdgcn_mfma_f32_16x16x32_bf16(a1[m][kh], bb[n][kh], acc[4 + m][n], 0, 0, 0);
    __builtin_amdgcn_s_setprio(0);
    BARF();

    // ---- P3: stage (t+2).A-top -> cur (all A reads of cur done at P2);
    //          read b[nh1]; MFMA mh0 x nh1
    STG_A1(cur, 0, k2);
    #pragma unroll
    for (int n = 0; n < 2; ++n)
      #pragma unroll
      for (int kh = 0; kh < 2; ++kh) LDB1(bb[n][kh], wn * 64 + (2 + n) * 16, kh);
    BARF();
    __builtin_amdgcn_s_setprio(1);
    #pragma unroll
    for (int m = 0; m < 4; ++m)
      #pragma unroll
      for (int n = 0; n < 2; ++n)
        #pragma unroll
        for (int kh = 0; kh < 2; ++kh)
          acc[m][2 + n] = __builtin_amdgcn_mfma_f32_16x16x32_bf16(a0[m][kh], bb[n][kh], acc[m][2 + n], 0, 0, 0);
    __builtin_amdgcn_s_setprio(0);
    BARF();

    // ---- P4: stage (t+2).A-bot -> cur; MFMA mh1 x nh1; counted vmcnt
    STG_A1(cur, 1, k2);
    __builtin_amdgcn_s_setprio(1);
    #pragma unroll
    for (int m = 0; m < 4; ++m)
      #pragma unroll
      for (int n = 0; n < 2; ++n)
        #pragma unroll
        for (int kh = 0; kh < 2; ++kh)
          acc[4 + m][2 + n] = __builtin_amdgcn_mfma_f32_16x16x32_bf16(a1[m][kh], bb[n][kh], acc[4 + m][2 + n], 0, 0, 0);
    __builtin_amdgcn_s_setprio(0);
    // 4 ops issued after (t+1).B-bot -> vmcnt(4) guarantees next tile resident
    asm volatile("s_waitcnt vmcnt(4)" ::: "memory");
    BARF();
  }

  // epilogue: acc[m][nf] (a) pairs with acc[m][2+nf] (g), same f
  int uoff = offs[e];
  const float* b1e = b1 + (size_t)e * FF2;
  #pragma unroll
  for (int nf = 0; nf < 2; ++nf) {
    int f = nt * 128 + wn * 32 + nf * 16 + l16;
    float ba = b1e[f];
    float bg = b1e[FF + f];
    #pragma unroll
    for (int m = 0; m < 8; ++m) {
      f32x4 av = acc[m][nf];
      f32x4 gv = acc[m][2 + nf];
      #pragma unroll
      for (int r = 0; r < 4; ++r) {
        int row = wm * 128 + m * 16 + quad * 4 + r;   // C-frag: row=quad*4+reg
        if (m0 + row < count) {
          float wv = w_list[e * T_TOK + m0 + row];    // L2-hot, one-time
          float aa = av[r] + ba;
          float gg = gv[r] + bg;
          float u = wv * aa * gg / (1.f + __expf(-gg));   // w * a * silu(g)
          U[(size_t)(uoff + m0 + row) * FF + f] = (bf16_t)u;
        }
      }
    }
  }
  // drain outstanding global_load_lds before the block retires its LDS
  asm volatile("s_waitcnt vmcnt(0)" ::: "memory");
}

// ---------------- GEMM2: U segment * W2t[e] -> plain stores into Y pair-rows
__global__ __launch_bounds__(256) void moe_gemm2(
    const bf16_t* __restrict__ U, const bf16_t* __restrict__ W2t,
    const int* __restrict__ cnt, const int* __restrict__ offs,
    float* __restrict__ Y,
    int e_base, long estride)
{
  int e = e_base + blockIdx.z;
  int count = cnt[e];
  int m0 = blockIdx.y * 128;
  if (m0 >= count) return;
  int n0 = blockIdx.x * 128;
  const bf16_t* W2e = W2t + (size_t)blockIdx.z * estride;

  __shared__ bf16_t As[128 * 64];
  __shared__ bf16_t Bs[128 * 64];
  int tid = threadIdx.x;
  int wave = tid >> 6, lane = tid & 63;
  int quad = lane >> 4, l16 = lane & 15;
  int rsub = lane >> 3;
  int swz  = (lane & 7) ^ rsub;             // XOR-swizzled global src chunk
  int uoff = offs[e];

  const bf16_t* asrc[4]; const bf16_t* bsrc[4];
  bf16_t* aldst[4]; bf16_t* bldst[4];
  #pragma unroll
  for (int s = 0; s < 4; ++s) {
    int inst = wave * 4 + s;
    int row = inst * 8 + rsub;
    asrc[s] = U   + (size_t)(uoff + m0 + row) * FF + swz * 8;  // U padded +128 rows
    bsrc[s] = W2e + (size_t)(n0 + row)        * FF + swz * 8;
    aldst[s] = As + inst * 512;
    bldst[s] = Bs + inst * 512;
  }

  f32x4 acc[2][8];
  #pragma unroll
  for (int i = 0; i < 2; ++i)
    #pragma unroll
    for (int j = 0; j < 8; ++j) acc[i][j] = (f32x4){0.f, 0.f, 0.f, 0.f};

  for (int k0 = 0; k0 < FF; k0 += 64) {
    __syncthreads();
    #pragma unroll
    for (int s = 0; s < 4; ++s) {
      gload_lds16(asrc[s] + k0, aldst[s]);
      gload_lds16(bsrc[s] + k0, bldst[s]);
    }
    __syncthreads();
    #pragma unroll
    for (int kh = 0; kh < 2; ++kh) {
      int so = ((kh * 4 + quad) ^ (l16 & 7)) * 8;   // swizzled chunk offset
      bf16x8 a0 = *(const bf16x8*)&As[(wave * 32      + l16) * 64 + so];
      bf16x8 a1 = *(const bf16x8*)&As[(wave * 32 + 16 + l16) * 64 + so];
      #pragma unroll
      for (int j = 0; j < 8; ++j) {
        bf16x8 b = *(const bf16x8*)&Bs[(j * 16 + l16) * 64 + so];
        acc[0][j] = __builtin_amdgcn_mfma_f32_16x16x32_bf16(a0, b, acc[0][j], 0, 0, 0);
        acc[1][j] = __builtin_amdgcn_mfma_f32_16x16x32_bf16(a1, b, acc[1][j], 0, 0, 0);
      }
    }
  }

  #pragma unroll
  for (int j = 0; j < 8; ++j) {
    int n = n0 + j * 16 + l16;
    #pragma unroll
    for (int i = 0; i < 2; ++i) {
      f32x4 av = acc[i][j];
      #pragma unroll
      for (int r = 0; r < 4; ++r) {
        int m = wave * 32 + i * 16 + quad * 4 + r;
        if (m0 + m < count)
          Y[(size_t)(uoff + m0 + m) * DMODEL + n] = av[r];
      }
    }
  }
}

// ---------------- combine: out[t] = Y[row0] + Y[row1] + w0*b2[e0] + w1*b2[e1]
__global__ __launch_bounds__(256) void moe_combine(
    const float* __restrict__ Y, const float* __restrict__ b2,
    const int* __restrict__ slot, const float* __restrict__ w_list,
    const int* __restrict__ offs, float* __restrict__ out)
{
  int t = blockIdx.x;
  int v0 = slot[2 * t], v1 = slot[2 * t + 1];
  int e0 = v0 >> 12, p0 = v0 & (T_TOK - 1);
  int e1 = v1 >> 12, p1 = v1 & (T_TOK - 1);
  int r0 = offs[e0] + p0, r1 = offs[e1] + p1;
  float w0 = w_list[v0], w1 = w_list[v1];
  int d = threadIdx.x * 4;
  f32x4 y0 = *(const f32x4*)&Y[(size_t)r0 * DMODEL + d];
  f32x4 y1 = *(const f32x4*)&Y[(size_t)r1 * DMODEL + d];
  f32x4 c0 = *(const f32x4*)&b2[(size_t)e0 * DMODEL + d];
  f32x4 c1 = *(const f32x4*)&b2[(size_t)e1 * DMODEL + d];
  *(f32x4*)&out[(size_t)t * DMODEL + d] = y0 + y1 + w0 * c0 + w1 * c1;
}

extern "C" void kernel_launch(void* const* d_in, const int* in_sizes, int n_in,
                              void* d_out, int out_size, void* d_ws, size_t ws_size,
                              hipStream_t stream)
{
  const float* x    = (const float*)d_in[0];
  const float* Wr   = (const float*)d_in[1];
  const float* temp = (const float*)d_in[2];
  const float* W1   = (const float*)d_in[3];
  const float* b1   = (const float*)d_in[4];
  const float* W2   = (const float*)d_in[5];
  const float* b2   = (const float*)d_in[6];
  float* out = (float*)d_out;

  char* ws = (char*)d_ws;
  size_t off = 0;
  auto alloc = [&](size_t b) { void* p = ws + off; off += (b + 255) & ~(size_t)255; return p; };
  bf16_t* xb  = (bf16_t*)alloc((size_t)T_TOK * DMODEL * 2);
  bf16_t* U   = (bf16_t*)alloc((size_t)(2 * T_TOK + 128) * FF * 2);  // +128 row pad for tile overread
  float*  Y   = (float*)alloc((size_t)(2 * T_TOK) * DMODEL * 4);
  int*   cnt  = (int*)alloc(256);
  int*   offs = (int*)alloc(256);
  int*   tok  = (int*)alloc((size_t)NEXP * T_TOK * 4);
  float* wl   = (float*)alloc((size_t)NEXP * T_TOK * 4);
  int*   slot = (int*)alloc((size_t)2 * T_TOK * 4);
  size_t base = off;
  const size_t W1T_FULL = (size_t)NEXP * FF2 * DMODEL * 2;
  const size_t W2T_FULL = (size_t)NEXP * DMODEL * FF * 2;
  bool batched = (ws_size >= base + W1T_FULL + W2T_FULL);  // constant per process: graph-safe

  hipMemsetAsync(cnt, 0, NEXP * sizeof(int), stream);
  moe_router<<<dim3(T_TOK / 4), dim3(256), 0, stream>>>(x, Wr, temp, xb, cnt, tok, wl, slot);
  moe_prefix<<<dim3(1), dim3(64), 0, stream>>>(cnt, offs);

  if (batched) {
    bf16_t* W1t = (bf16_t*)alloc(W1T_FULL);
    bf16_t* W2t = (bf16_t*)alloc(W2T_FULL);
    tcast_fast<<<dim3(FF2 / 64, DMODEL / 64, NEXP), dim3(256), 0, stream>>>(W1, W1t, DMODEL, FF2);
    tcast_fast<<<dim3(DMODEL / 64, FF / 64, NEXP), dim3(256), 0, stream>>>(W2, W2t, FF, DMODEL);
    moe_gemm1<<<dim3(FF / 128, T_TOK / 256, NEXP), dim3(512), 0, stream>>>(
        xb, W1t, b1, cnt, offs, tok, wl, U, 0, (long)FF2 * DMODEL);
    moe_gemm2<<<dim3(DMODEL / 128, T_TOK / 128, NEXP), dim3(256), 0, stream>>>(
        U, W2t, cnt, offs, Y, 0, (long)DMODEL * FF);
  } else {
    // ws too small for all transposed weights: rotate one-expert buffers (stream-serial)
    bf16_t* W1t = (bf16_t*)alloc((size_t)FF2 * DMODEL * 2);
    bf16_t* W2t = (bf16_t*)alloc((size_t)DMODEL * FF * 2);
    for (int e = 0; e < NEXP; ++e) {
      tcast_fast<<<dim3(FF2 / 64, DMODEL / 64, 1), dim3(256), 0, stream>>>(
          W1 + (size_t)e * DMODEL * FF2, W1t, DMODEL, FF2);
      moe_gemm1<<<dim3(FF / 128, T_TOK / 256, 1), dim3(512), 0, stream>>>(
          xb, W1t, b1, cnt, offs, tok, wl, U, e, 0);
    }
    for (int e = 0; e < NEXP; ++e) {
      tcast_fast<<<dim3(DMODEL / 64, FF / 64, 1), dim3(256), 0, stream>>>(
          W2 + (size_t)e * FF * DMODEL, W2t, FF, DMODEL);
      moe_gemm2<<<dim3(DMODEL / 128, T_TOK / 128, 1), dim3(256), 0, stream>>>(
          U, W2t, cnt, offs, Y, e, 0);
    }
  }
  moe_combine<<<dim3(T_TOK), dim3(256), 0, stream>>>(Y, b2, slot, wl, offs, out);
}